// Round 11
// baseline (161.262 us; speedup 1.0000x reference)
//
#include <hip/hip_runtime.h>
#include <hip/hip_bf16.h>

#define DM 1024
#define HID 64
#define NSTEP 6
#define RSTEP (1.0f/6.0f)

using short8  = __attribute__((ext_vector_type(8))) short;
using short4v = __attribute__((ext_vector_type(4))) short;
using f32x4   = __attribute__((ext_vector_type(4))) float;

// workspace byte offsets
#define WS_W1P 0          // 1024x64 bf16 packed A-frags (131072 B)
#define WS_W2P 131072     // 64x1024 bf16 packed A-frags (131072 B)
#define WS_GP  262144     // 64x64 bf16 packed A-frags (8192 B)
#define WS_U   270336     // 64 f32  (u = b2 @ W1k)

// LDS byte offsets (total 25344 B -> 4 blocks/CU with room to spare)
#define L_B2 0            // b2 f32[1024] (4096)
#define L_GP 4096         // G packed frags (8192)
#define L_U  12288        // u f32[64] (256)
#define L_B1 12544        // b1 f32[64] (256)
#define L_WT 12800        // W1 time row f32[64] (256)
#define L_SZ 13056        // sz share buf [16][64] f32 (4096, prologue only)
#define L_HW 17152        // per-WAVE H buf: 4 x [16][64] bf16 (4 x 2048)
#define LDS_TOTAL 25344

// Intra-wave LDS ordering only (R5-proven): the DS pipe is in-order per
// wave; this fence stops compiler reordering across the exchange. The
// step loop has ZERO s_barrier — each wave's chain is independent.
#define FENCE() asm volatile("s_waitcnt lgkmcnt(0)" ::: "memory")

__device__ __forceinline__ short f2bf(float f) {   // RNE via HW cvt
    __hip_bfloat16 h = __float2bfloat16(f);
    short s;
    __builtin_memcpy(&s, &h, 2);
    return s;
}
__device__ __forceinline__ float ftanh(float x) {
    x = fminf(fmaxf(x, -10.f), 10.f);
    float e = __expf(2.f * x);
    return __fdividef(e - 1.f, e + 1.f);
}

// ---------------- prep: pack weights to MFMA fragment layout ----------------
__global__ void k_prep(const float* __restrict__ W1, const float* __restrict__ W2,
                       const float* __restrict__ b2,
                       short* __restrict__ W1P, short* __restrict__ W2P,
                       short* __restrict__ GP, float* __restrict__ U) {
    __shared__ float red[4][64];
    int b = blockIdx.x;
    int t = threadIdx.x;           // 256 threads
    int l = t & 63, q4 = t >> 6;
    if (b < 128) {                 // W1k (1024x64) -> W1P[kk<32][c<4][l][8]
        if (t < 64) {
            int kk = b >> 2, c = b & 3;
            int col = c * 16 + (l & 15);
            int kb = kk * 32 + ((l >> 4) << 3);
            short8 v;
            #pragma unroll
            for (int i = 0; i < 8; ++i) v[i] = f2bf(W1[(kb + i) * HID + col]);
            *(short8*)(W1P + (((kk * 4 + c) * 64) + l) * 8) = v;
        }
    } else if (b < 256) {          // W2 (64x1024) -> W2P[kk2<2][ct<64][l][8]
        if (t < 64) {
            int bb = b - 128;
            int kk2 = bb >> 6, ct = bb & 63;
            int col = ct * 16 + (l & 15);
            int kb = kk2 * 32 + ((l >> 4) << 3);
            short8 v;
            #pragma unroll
            for (int i = 0; i < 8; ++i) v[i] = f2bf(W2[(kb + i) * DM + col]);
            *(short8*)(W2P + (((kk2 * 64 + ct) * 64) + l) * 8) = v;
        }
    } else if (b < 320) {          // G[j][i] = sum_d W2[j][d]*W1[d][i]; j = b-256
        int j = b - 256;
        float acc = 0.f;
        #pragma unroll 8
        for (int d = q4 * 256; d < q4 * 256 + 256; ++d)
            acc += W2[j * DM + d] * W1[d * HID + l];
        red[q4][l] = acc;
        __syncthreads();
        if (t < 64) {
            float a = red[0][l] + red[1][l] + red[2][l] + red[3][l];
            int kk = j >> 5, lk = (j >> 3) & 3, ii = j & 7, c = l >> 4, lo = l & 15;
            GP[(((kk * 4 + c) * 64) + lk * 16 + lo) * 8 + ii] = f2bf(a);
        }
    } else {                       // u[i] = sum_d b2[d]*W1[d][i]
        float acc = 0.f;
        #pragma unroll 8
        for (int d = q4 * 256; d < q4 * 256 + 256; ++d)
            acc += b2[d] * W1[d * HID + l];
        red[q4][l] = acc;
        __syncthreads();
        if (t < 64) U[l] = red[0][l] + red[1][l] + red[2][l] + red[3][l];
    }
}

// ---------------- fused RK4 neural-ODE kernel (barrier-free steps) ----------
// Block: 256 thr (4 waves), 16 rows, grid 1024 -> 4 blocks/CU, 1 round.
// Incremental sz: sz' = sz + Hb@G + h*u; GEMM1 once in prologue
// (distributed 1 c-tile/wave, shared via L_SZ + one __syncthreads).
// STEP LOOP HAS ZERO BARRIERS: every wave REDUNDANTLY computes all 4 RK4
// stages for the block's 16 rows (full 64 hid cols; sz[4] per wave), so
// P6's Hb B-frags are wave-local. D-layout -> B-frag exchange goes through
// the wave's PRIVATE 2KB H-buffer with lgkmcnt-only FENCEs (in-order DS
// pipe; R5-proven correct). Stage VALU is 4x redundant but cheap; the win
// is 16 fully-independent wave chains per CU (no barrier convoy, R10's
// idle-wave lesson inverted).
// P6: R7's proven shape — wave w owns z cols [w*256,+256), z[16]=64 regs.
// H-buf accesses XOR-swizzled by (l15&7)<<4 (else D-write is 16-way bank
// conflict). Consts (u/b1/w1t/b2/G) in LDS, read per-stage (reg relief).
// MFMA: A = packed weights (M = out-col), B = z/H rows (N = row).
// D: m=(lane>>4)*4+reg (out-col), n=lane&15 (row).
// ALLOCATION: amdgpu_waves_per_eu(2,4) — the only attr honored at
// VGPR=128 without spill (10-round ledger).
__global__ __launch_bounds__(256) __attribute__((amdgpu_waves_per_eu(2, 4)))
void k_ode(
        const float* __restrict__ X, const float* __restrict__ W1,
        const float* __restrict__ b1, const float* __restrict__ b2,
        const short* __restrict__ W1P, const short* __restrict__ W2P,
        const short* __restrict__ GP, const float* __restrict__ U,
        float* __restrict__ OUT) {
    extern __shared__ char smem[];
    const int t = threadIdx.x;
    const int lane = t & 63;
    const int w = t >> 6;                    // 0..3
    const int hq = lane >> 4;
    const int l15 = lane & 15;
    const size_t row0 = (size_t)blockIdx.x * 16;
    const int SW = (l15 & 7) << 4;           // H-buf XOR swizzle
    char* hw = smem + L_HW + (w << 11);      // this wave's private H buf

    // ---- stage consts into LDS ----
    *(f32x4*)(smem + L_B2 + t * 16) = *(const f32x4*)(b2 + t * 4);
    *(f32x4*)(smem + L_GP + t * 32)      = *(const f32x4*)((const float*)GP + t * 8);
    *(f32x4*)(smem + L_GP + t * 32 + 16) = *(const f32x4*)((const float*)GP + t * 8 + 4);
    if (t < 64)       *(float*)(smem + L_U  + t * 4)         = U[t];
    else if (t < 128) *(float*)(smem + L_B1 + (t - 64) * 4)  = b1[t - 64];
    else if (t < 192) *(float*)(smem + L_WT + (t - 128) * 4) = W1[DM * HID + (t - 128)];

    // ---- z master: lane owns row l15, cols w*256 + q*16 + hq*4 ----
    f32x4 z[16];
    {
        const float* zr = X + (row0 + l15) * DM + w * 256;
        #pragma unroll
        for (int q = 0; q < 16; ++q)
            z[q] = *(const f32x4*)(zr + q * 16 + hq * 4);
    }

    // ---- prologue GEMM1 (distributed, c = w): share sz via L_SZ ----
    {
        const float* xrow = X + (row0 + l15) * DM;
        const short8* wp = (const short8*)W1P + (w * 64 + lane);
        f32x4 a0 = (f32x4){0.f, 0.f, 0.f, 0.f};
        f32x4 a1 = (f32x4){0.f, 0.f, 0.f, 0.f};
        #pragma unroll 4
        for (int kk = 0; kk < 32; kk += 2) {
            const float* xp = xrow + (kk << 5) + (hq << 3);
            f32x4 lo0 = *(const f32x4*)(xp);
            f32x4 hi0 = *(const f32x4*)(xp + 4);
            f32x4 lo1 = *(const f32x4*)(xp + 32);
            f32x4 hi1 = *(const f32x4*)(xp + 36);
            short8 zf0, zf1;
            #pragma unroll
            for (int j = 0; j < 4; ++j) {
                zf0[j] = f2bf(lo0[j]); zf0[4 + j] = f2bf(hi0[j]);
                zf1[j] = f2bf(lo1[j]); zf1[4 + j] = f2bf(hi1[j]);
            }
            a0 = __builtin_amdgcn_mfma_f32_16x16x32_bf16(wp[kk * 256],       zf0, a0, 0, 0, 0);
            a1 = __builtin_amdgcn_mfma_f32_16x16x32_bf16(wp[(kk + 1) * 256], zf1, a1, 0, 0, 0);
        }
        *(f32x4*)(smem + L_SZ + l15 * 256 + w * 64 + hq * 16) = a0 + a1;
    }
    __syncthreads();               // the ONLY block-wide barrier

    // full sz per wave (redundant copy)
    f32x4 sz[4];
    #pragma unroll
    for (int c = 0; c < 4; ++c)
        sz[c] = *(const f32x4*)(smem + L_SZ + l15 * 256 + c * 64 + hq * 16);

    const short8* w2p8 = (const short8*)W2P;

    for (int s = 0; s < NSTEP; ++s) {
        const float tcur = RSTEP * (float)s;
        f32x4 hsum[4];
        short8 hb0, hb1;

        // stage 1: H1 = tanh(sz + t*w1t + b1), all 4 c-tiles, wave-local
        #pragma unroll
        for (int c = 0; c < 4; ++c) {
            int cb = (c * 16 + hq * 4) * 4;
            f32x4 b14 = *(const f32x4*)(smem + L_B1 + cb);
            f32x4 wt4 = *(const f32x4*)(smem + L_WT + cb);
            short4v hc;
            #pragma unroll
            for (int j = 0; j < 4; ++j) {
                float T = sz[c][j] + tcur * wt4[j] + b14[j];
                float h = ftanh(T);
                hsum[c][j] = h;
                hc[j] = f2bf(h);
            }
            *(short4v*)(hw + ((l15 * 128 + c * 32 + hq * 8) ^ SW)) = hc;
        }
        FENCE();
        hb0 = *(const short8*)(hw + ((l15 * 128 + hq * 16) ^ SW));
        hb1 = *(const short8*)(hw + ((l15 * 128 + 64 + hq * 16) ^ SW));

        // stages 2..4 via H@G (G from LDS), wave-local, FENCE-only
        #pragma unroll
        for (int st = 0; st < 3; ++st) {
            const float c_i = (st == 2) ? RSTEP : (0.5f * RSTEP);
            const float t_i = tcur + ((st == 2) ? RSTEP : (0.5f * RSTEP));
            const float w_i = (st == 2) ? 1.f : 2.f;
            #pragma unroll
            for (int c = 0; c < 4; ++c) {
                short8 gf0 = *(const short8*)(smem + L_GP + ((c)     * 64 + lane) * 16);
                short8 gf1 = *(const short8*)(smem + L_GP + ((4 + c) * 64 + lane) * 16);
                f32x4 dd = (f32x4){0.f, 0.f, 0.f, 0.f};
                dd = __builtin_amdgcn_mfma_f32_16x16x32_bf16(gf0, hb0, dd, 0, 0, 0);
                dd = __builtin_amdgcn_mfma_f32_16x16x32_bf16(gf1, hb1, dd, 0, 0, 0);
                int cb = (c * 16 + hq * 4) * 4;
                f32x4 u4  = *(const f32x4*)(smem + L_U  + cb);
                f32x4 b14 = *(const f32x4*)(smem + L_B1 + cb);
                f32x4 wt4 = *(const f32x4*)(smem + L_WT + cb);
                short4v hc;
                #pragma unroll
                for (int j = 0; j < 4; ++j) {
                    float T = sz[c][j] + c_i * (dd[j] + u4[j]) + t_i * wt4[j] + b14[j];
                    float h = ftanh(T);
                    hsum[c][j] += w_i * h;
                    hc[j] = (st < 2) ? f2bf(h) : f2bf(hsum[c][j] * (RSTEP / 6.f));
                }
                *(short4v*)(hw + ((l15 * 128 + c * 32 + hq * 8) ^ SW)) = hc;
            }
            FENCE();
            hb0 = *(const short8*)(hw + ((l15 * 128 + hq * 16) ^ SW));
            hb1 = *(const short8*)(hw + ((l15 * 128 + 64 + hq * 16) ^ SW));
        }
        // hb0/hb1 now hold Hb = (h/6)*Hsum B-frags (wave-local)

        // incremental sz update: sz += Hb@G + h*u
        #pragma unroll
        for (int c = 0; c < 4; ++c) {
            short8 gf0 = *(const short8*)(smem + L_GP + ((c)     * 64 + lane) * 16);
            short8 gf1 = *(const short8*)(smem + L_GP + ((4 + c) * 64 + lane) * 16);
            f32x4 dd = (f32x4){0.f, 0.f, 0.f, 0.f};
            dd = __builtin_amdgcn_mfma_f32_16x16x32_bf16(gf0, hb0, dd, 0, 0, 0);
            dd = __builtin_amdgcn_mfma_f32_16x16x32_bf16(gf1, hb1, dd, 0, 0, 0);
            f32x4 u4 = *(const f32x4*)(smem + L_U + (c * 16 + hq * 4) * 4);
            #pragma unroll
            for (int j = 0; j < 4; ++j)
                sz[c][j] += dd[j] + RSTEP * u4[j];
        }

        // P6 (R7 shape): z += Hb @ W2 + h*b2 on cols [w*256,+256)
        if (s < NSTEP - 1) {
            #pragma unroll
            for (int q = 0; q < 16; ++q) {
                int ct = w * 16 + q;
                short8 wa = w2p8[ct * 64 + lane];
                short8 wb = w2p8[(64 + ct) * 64 + lane];
                f32x4 b2v = *(const f32x4*)(smem + L_B2 + (ct * 16 + hq * 4) * 4);
                f32x4 p = (f32x4){0.f, 0.f, 0.f, 0.f};
                p = __builtin_amdgcn_mfma_f32_16x16x32_bf16(wa, hb0, p, 0, 0, 0);
                p = __builtin_amdgcn_mfma_f32_16x16x32_bf16(wb, hb1, p, 0, 0, 0);
                #pragma unroll
                for (int j = 0; j < 4; ++j)
                    z[q][j] += p[j] + RSTEP * b2v[j];
            }
        } else {   // last step: final z straight from regs to OUT (f32)
            float* orow = OUT + (row0 + l15) * DM + w * 256;
            #pragma unroll
            for (int q = 0; q < 16; ++q) {
                int ct = w * 16 + q;
                short8 wa = w2p8[ct * 64 + lane];
                short8 wb = w2p8[(64 + ct) * 64 + lane];
                f32x4 b2v = *(const f32x4*)(smem + L_B2 + (ct * 16 + hq * 4) * 4);
                f32x4 p = (f32x4){0.f, 0.f, 0.f, 0.f};
                p = __builtin_amdgcn_mfma_f32_16x16x32_bf16(wa, hb0, p, 0, 0, 0);
                p = __builtin_amdgcn_mfma_f32_16x16x32_bf16(wb, hb1, p, 0, 0, 0);
                f32x4 nv;
                #pragma unroll
                for (int j = 0; j < 4; ++j)
                    nv[j] = z[q][j] + p[j] + RSTEP * b2v[j];
                *(f32x4*)(orow + q * 16 + hq * 4) = nv;
            }
        }
    }
}

extern "C" void kernel_launch(void* const* d_in, const int* in_sizes, int n_in,
                              void* d_out, int out_size, void* d_ws, size_t ws_size,
                              hipStream_t stream) {
    (void)in_sizes; (void)n_in; (void)out_size; (void)ws_size;
    const float* X  = (const float*)d_in[0];
    const float* W1 = (const float*)d_in[1];
    const float* b1 = (const float*)d_in[2];
    const float* W2 = (const float*)d_in[3];
    const float* b2 = (const float*)d_in[4];
    float* OUT = (float*)d_out;
    short* W1P = (short*)((char*)d_ws + WS_W1P);
    short* W2P = (short*)((char*)d_ws + WS_W2P);
    short* GP  = (short*)((char*)d_ws + WS_GP);
    float* U   = (float*)((char*)d_ws + WS_U);

    k_prep<<<321, 256, 0, stream>>>(W1, W2, b2, W1P, W2P, GP, U);
    k_ode<<<1024, 256, LDS_TOTAL, stream>>>(X, W1, b1, b2, W1P, W2P, GP, U, OUT);
}

// Round 12
// 78.509 us; speedup vs baseline: 2.0540x; 2.0540x over previous
//
#include <hip/hip_runtime.h>
#include <hip/hip_bf16.h>

#define DM 1024
#define HID 64
#define NSTEP 6
#define RSTEP (1.0f/6.0f)

using short8  = __attribute__((ext_vector_type(8))) short;
using short4v = __attribute__((ext_vector_type(4))) short;
using f32x4   = __attribute__((ext_vector_type(4))) float;

// workspace byte offsets
#define WS_W1P 0          // 1024x64 bf16 packed A-frags (131072 B)
#define WS_W2P 131072     // 64x1024 bf16 packed A-frags (131072 B)
#define WS_GP  262144     // 64x64 bf16 packed A-frags (8192 B)
#define WS_U   270336     // 64 f32  (u = b2 @ W1k)

// LDS byte offsets (total 11008 B — tiny; occupancy is VGPR-bound)
#define L_H0 0            // H ping  [16][72] bf16, pitch 144 (2304)
#define L_H1 2304         // H pong
#define L_HB 4608         // Hb (per-step) / bf16(S) (final) — sz-upd + epilogue
#define L_B2 6912         // b2 staged f32[1024] (4096)
#define LDS_TOTAL 11008
#define HP 144

// LDS-only barrier: order LDS ops, do NOT drain vmcnt (global loads stay
// in flight across barriers; cross-wave data passes only through LDS).
#define BAR() asm volatile("s_waitcnt lgkmcnt(0)\n\ts_barrier" ::: "memory")

__device__ __forceinline__ short f2bf(float f) {   // RNE via HW cvt
    __hip_bfloat16 h = __float2bfloat16(f);
    short s;
    __builtin_memcpy(&s, &h, 2);
    return s;
}
__device__ __forceinline__ float ftanh(float x) {
    x = fminf(fmaxf(x, -10.f), 10.f);
    float e = __expf(2.f * x);
    return __fdividef(e - 1.f, e + 1.f);
}

// ---------------- prep: pack weights to MFMA fragment layout ----------------
// A-frag layout for mfma_f32_16x16x32_bf16: lane l holds M-row (l&15),
// k = (l>>4)*8 + i (8 consecutive k). Packed so each lane loads one short8.
__global__ void k_prep(const float* __restrict__ W1, const float* __restrict__ W2,
                       const float* __restrict__ b2,
                       short* __restrict__ W1P, short* __restrict__ W2P,
                       short* __restrict__ GP, float* __restrict__ U) {
    __shared__ float red[4][64];
    int b = blockIdx.x;
    int t = threadIdx.x;           // 256 threads
    int l = t & 63, q4 = t >> 6;
    if (b < 128) {                 // W1k (1024x64) -> W1P[kk<32][c<4][l][8]
        if (t < 64) {
            int kk = b >> 2, c = b & 3;
            int col = c * 16 + (l & 15);
            int kb = kk * 32 + ((l >> 4) << 3);
            short8 v;
            #pragma unroll
            for (int i = 0; i < 8; ++i) v[i] = f2bf(W1[(kb + i) * HID + col]);
            *(short8*)(W1P + (((kk * 4 + c) * 64) + l) * 8) = v;
        }
    } else if (b < 256) {          // W2 (64x1024) -> W2P[kk2<2][ct<64][l][8]
        if (t < 64) {
            int bb = b - 128;
            int kk2 = bb >> 6, ct = bb & 63;
            int col = ct * 16 + (l & 15);
            int kb = kk2 * 32 + ((l >> 4) << 3);
            short8 v;
            #pragma unroll
            for (int i = 0; i < 8; ++i) v[i] = f2bf(W2[(kb + i) * DM + col]);
            *(short8*)(W2P + (((kk2 * 64 + ct) * 64) + l) * 8) = v;
        }
    } else if (b < 320) {          // G[j][i] = sum_d W2[j][d]*W1[d][i]; j = b-256
        int j = b - 256;
        float acc = 0.f;
        #pragma unroll 8
        for (int d = q4 * 256; d < q4 * 256 + 256; ++d)
            acc += W2[j * DM + d] * W1[d * HID + l];
        red[q4][l] = acc;
        __syncthreads();
        if (t < 64) {
            float a = red[0][l] + red[1][l] + red[2][l] + red[3][l];
            int kk = j >> 5, lk = (j >> 3) & 3, ii = j & 7, c = l >> 4, lo = l & 15;
            GP[(((kk * 4 + c) * 64) + lk * 16 + lo) * 8 + ii] = f2bf(a);
        }
    } else {                       // u[i] = sum_d b2[d]*W1[d][i]
        float acc = 0.f;
        #pragma unroll 8
        for (int d = q4 * 256; d < q4 * 256 + 256; ++d)
            acc += b2[d] * W1[d * HID + l];
        red[q4][l] = acc;
        __syncthreads();
        if (t < 64) U[l] = red[0][l] + red[1][l] + red[2][l] + red[3][l];
    }
}

// ---------------- fused RK4 neural-ODE kernel (deferred z) ----------------
// ALGEBRA (the whole point): with incremental sz (sz' = sz + Hb@G + h*u),
// z is never read inside the step loop. Its update is linear in Hb, so
//   z_T = x + S @ W2 + b2,   S = sum_s (h/6)*Hsum_s   (f32, exact accum)
// -> the big z GEMM runs ONCE in the epilogue; the step loop is only the
// 4 tiny stage phases + a 2-MFMA sz update. No global loads in the loop,
// no z registers (R9's 64 VGPRs freed), ~7.5 GFLOP total vs R9's ~28.
// Block: 256 thr (4 waves), 16 rows, grid 1024 -> 4 blocks/CU, 1 round,
// 4 independent barrier chains per CU.
// Stage tiling (R7-proven): wave w owns hid c-tile w: rows l15 (D-layout
// n=lane&15=row, m=(lane>>4)*4+reg=col). sz and ssum live in the D-layout
// regs of their computing wave — no exchange except H via LDS (4 BAR/step).
// Epilogue: bf16(S) through L_HB (stage-4 path), wave w -> z cols
// [w*256,+256); x re-read from global (L3-resident since prologue).
// ALLOCATION: amdgpu_waves_per_eu(2,4) — only attr honored at VGPR<=128
// with no spill (11-round ledger).
__global__ __launch_bounds__(256) __attribute__((amdgpu_waves_per_eu(2, 4)))
void k_ode(
        const float* __restrict__ X, const float* __restrict__ W1,
        const float* __restrict__ b1, const float* __restrict__ b2,
        const short* __restrict__ W1P, const short* __restrict__ W2P,
        const short* __restrict__ GP, const float* __restrict__ U,
        float* __restrict__ OUT) {
    extern __shared__ char smem[];
    const int t = threadIdx.x;
    const int lane = t & 63;
    const int w = t >> 6;                    // 0..3
    const int hq = lane >> 4;
    const int l15 = lane & 15;
    const int hcol0 = w * 16 + hq * 4;       // hid-col base (stage epilogues)
    const size_t row0 = (size_t)blockIdx.x * 16;

    // stage b2 -> LDS (first read is in the epilogue; any BAR covers it)
    *(f32x4*)(smem + L_B2 + t * 16) = *(const f32x4*)(b2 + t * 4);

    // per-lane persistent constants (L2-hot broadcasts)
    f32x4 u4   = *(const f32x4*)(U + hcol0);
    f32x4 b14  = *(const f32x4*)(b1 + hcol0);
    f32x4 w1t4 = *(const f32x4*)(W1 + DM * HID + hcol0);   // time row of W1
    short8 gf0 = *(const short8*)(GP + (w * 64 + lane) * 8);
    short8 gf1 = *(const short8*)(GP + ((4 + w) * 64 + lane) * 8);

    // ---- prologue GEMM1 (once): sz = x @ W1k, x B-frags from global ----
    f32x4 sz;
    {
        const float* xrow = X + (row0 + l15) * DM;
        const short8* wp = (const short8*)W1P + (w * 64 + lane);
        f32x4 a0 = (f32x4){0.f, 0.f, 0.f, 0.f};
        f32x4 a1 = (f32x4){0.f, 0.f, 0.f, 0.f};
        #pragma unroll 4
        for (int kk = 0; kk < 32; kk += 2) {
            const float* xp = xrow + (kk << 5) + (hq << 3);
            f32x4 lo0 = *(const f32x4*)(xp);
            f32x4 hi0 = *(const f32x4*)(xp + 4);
            f32x4 lo1 = *(const f32x4*)(xp + 32);
            f32x4 hi1 = *(const f32x4*)(xp + 36);
            short8 zf0, zf1;
            #pragma unroll
            for (int j = 0; j < 4; ++j) {
                zf0[j] = f2bf(lo0[j]); zf0[4 + j] = f2bf(hi0[j]);
                zf1[j] = f2bf(lo1[j]); zf1[4 + j] = f2bf(hi1[j]);
            }
            a0 = __builtin_amdgcn_mfma_f32_16x16x32_bf16(wp[kk * 256],       zf0, a0, 0, 0, 0);
            a1 = __builtin_amdgcn_mfma_f32_16x16x32_bf16(wp[(kk + 1) * 256], zf1, a1, 0, 0, 0);
        }
        sz = a0 + a1;
    }

    f32x4 ssum = (f32x4){0.f, 0.f, 0.f, 0.f};   // S accumulator (f32, exact)

    for (int s = 0; s < NSTEP; ++s) {
        const float tcur = RSTEP * (float)s;

        // stage 1: H1 = tanh(sz + t*w1t + b1) -> H0
        f32x4 hsum;
        {
            short4v hc;
            #pragma unroll
            for (int j = 0; j < 4; ++j) {
                float T = sz[j] + tcur * w1t4[j] + b14[j];
                float h = ftanh(T);
                hsum[j] = h;
                hc[j] = f2bf(h);
            }
            *(short4v*)(smem + L_H0 + l15 * HP + hcol0 * 2) = hc;
        }
        BAR();

        // stages 2..4 via tiny H@G GEMM (G = W2@W1k, frags pinned in regs)
        #pragma unroll
        for (int st = 0; st < 3; ++st) {
            const float c_i = (st == 2) ? RSTEP : (0.5f * RSTEP);
            const float t_i = tcur + ((st == 2) ? RSTEP : (0.5f * RSTEP));
            const float w_i = (st == 2) ? 1.f : 2.f;
            const int rbuf = (st & 1) ? L_H1 : L_H0;
            const int wbuf = (st & 1) ? L_H0 : L_H1;

            short8 hf0 = *(const short8*)(smem + rbuf + l15 * HP + (hq << 4));
            short8 hf1 = *(const short8*)(smem + rbuf + l15 * HP + 64 + (hq << 4));
            f32x4 dd = (f32x4){0.f, 0.f, 0.f, 0.f};
            dd = __builtin_amdgcn_mfma_f32_16x16x32_bf16(gf0, hf0, dd, 0, 0, 0);
            dd = __builtin_amdgcn_mfma_f32_16x16x32_bf16(gf1, hf1, dd, 0, 0, 0);
            short4v hc;
            #pragma unroll
            for (int j = 0; j < 4; ++j) {
                float T = sz[j] + c_i * (dd[j] + u4[j]) + t_i * w1t4[j] + b14[j];
                float h = ftanh(T);
                hsum[j] += w_i * h;
                hc[j] = f2bf(h);
            }
            if (st < 2) {
                *(short4v*)(smem + wbuf + l15 * HP + hcol0 * 2) = hc;
            } else {
                // S += (h/6)*Hsum (exact, f32). Write per-step Hb for the
                // sz update; on the LAST step write bf16(S) instead — it
                // feeds the epilogue GEMM through the same L_HB path.
                short4v hb4;
                #pragma unroll
                for (int j = 0; j < 4; ++j) {
                    ssum[j] += hsum[j] * (RSTEP / 6.f);
                    hb4[j] = (s < NSTEP - 1) ? f2bf(hsum[j] * (RSTEP / 6.f))
                                             : f2bf(ssum[j]);
                }
                *(short4v*)(smem + L_HB + l15 * HP + hcol0 * 2) = hb4;
            }
            BAR();
        }

        // incremental sz update: sz += Hb@G + h*u  (2 MFMA, wave-local)
        if (s < NSTEP - 1) {
            short8 hb0 = *(const short8*)(smem + L_HB + l15 * HP + (hq << 4));
            short8 hb1 = *(const short8*)(smem + L_HB + l15 * HP + 64 + (hq << 4));
            f32x4 d = (f32x4){0.f, 0.f, 0.f, 0.f};
            d = __builtin_amdgcn_mfma_f32_16x16x32_bf16(gf0, hb0, d, 0, 0, 0);
            d = __builtin_amdgcn_mfma_f32_16x16x32_bf16(gf1, hb1, d, 0, 0, 0);
            #pragma unroll
            for (int j = 0; j < 4; ++j)
                sz[j] += d[j] + RSTEP * u4[j];
        }
    }

    // ---- epilogue (once): z_T = x + S @ W2 + b2, wave w -> cols [w*256,+256)
    {
        short8 sb0 = *(const short8*)(smem + L_HB + l15 * HP + (hq << 4));
        short8 sb1 = *(const short8*)(smem + L_HB + l15 * HP + 64 + (hq << 4));
        const short8* w2p8 = (const short8*)W2P;
        const float* xrow = X + (row0 + l15) * DM + w * 256;   // L3-resident
        float* orow = OUT + (row0 + l15) * DM + w * 256;
        #pragma unroll 4
        for (int q = 0; q < 16; ++q) {
            int ct = w * 16 + q;
            short8 wa = w2p8[ct * 64 + lane];
            short8 wb = w2p8[(64 + ct) * 64 + lane];
            f32x4 p = (f32x4){0.f, 0.f, 0.f, 0.f};
            p = __builtin_amdgcn_mfma_f32_16x16x32_bf16(wa, sb0, p, 0, 0, 0);
            p = __builtin_amdgcn_mfma_f32_16x16x32_bf16(wb, sb1, p, 0, 0, 0);
            f32x4 b2v = *(const f32x4*)(smem + L_B2 + (ct * 16 + hq * 4) * 4);
            f32x4 xv  = *(const f32x4*)(xrow + q * 16 + hq * 4);
            f32x4 nv;
            #pragma unroll
            for (int j = 0; j < 4; ++j)
                nv[j] = xv[j] + p[j] + b2v[j];       // sum of h*b2 over 6 steps = b2
            *(f32x4*)(orow + q * 16 + hq * 4) = nv;
        }
    }
}

extern "C" void kernel_launch(void* const* d_in, const int* in_sizes, int n_in,
                              void* d_out, int out_size, void* d_ws, size_t ws_size,
                              hipStream_t stream) {
    (void)in_sizes; (void)n_in; (void)out_size; (void)ws_size;
    const float* X  = (const float*)d_in[0];
    const float* W1 = (const float*)d_in[1];
    const float* b1 = (const float*)d_in[2];
    const float* W2 = (const float*)d_in[3];
    const float* b2 = (const float*)d_in[4];
    float* OUT = (float*)d_out;
    short* W1P = (short*)((char*)d_ws + WS_W1P);
    short* W2P = (short*)((char*)d_ws + WS_W2P);
    short* GP  = (short*)((char*)d_ws + WS_GP);
    float* U   = (float*)((char*)d_ws + WS_U);

    k_prep<<<321, 256, 0, stream>>>(W1, W2, b2, W1P, W2P, GP, U);
    k_ode<<<1024, 256, LDS_TOTAL, stream>>>(X, W1, b1, b2, W1P, W2P, GP, U, OUT);
}